// Round 14
// baseline (233.291 us; speedup 1.0000x reference)
//
#include <hip/hip_runtime.h>
#include <math.h>

// Problem constants
#define BB 4
#define LLL 1024
#define DDD 768
#define HHH 12
#define EEE 30
#define MMM 60
#define PPP 870
#define RRR 97
#define NNODE 120   // B*E
#define NPAIR 3480  // B*P
#define NEDGE 3600  // NPAIR + NNODE self loops
#define FMIN 1e-10f

typedef __attribute__((ext_vector_type(8))) __bf16 bf16x8;
typedef __attribute__((ext_vector_type(8))) short short8;
typedef __attribute__((ext_vector_type(8))) _Float16 f16x8;
typedef __attribute__((ext_vector_type(4))) float f32x4;
typedef __attribute__((ext_vector_type(4))) unsigned short u16x4;

static __device__ __forceinline__ unsigned short f2bf(float v) {
  return __builtin_bit_cast(unsigned short, (__bf16)v);
}
static __device__ __forceinline__ unsigned short f2h(float v) {
  return __builtin_bit_cast(unsigned short, (_Float16)v);
}
static __device__ __forceinline__ float bf2f(unsigned short u) {
  unsigned int x = ((unsigned int)u) << 16;
  return __builtin_bit_cast(float, x);
}

// ===========================================================================
// FUSED PREP KERNEL (round-13 version: long blocks first).
// ===========================================================================
struct PrepArgs {
  const float *Wrel, *context, *mmap, *emap;
  const float *wsrc[6];
  unsigned short *tW, *ctxT, *xb;
  unsigned short *wdst[6];
  int *nzl, *nzc;
  float *nzw;
};

#define NB_EM    NNODE
#define NB_ENT   NNODE
#define NB_WPREP 768
#define NB_CTX   (24 * 32 * BB)
#define NB_WT    (24 * 48 * 6)

static __device__ void body_em(int be, const float* __restrict__ emap,
                               const float* __restrict__ mmap,
                               int* __restrict__ nzl, float* __restrict__ nzw,
                               int* __restrict__ nzc) {
  __shared__ float em_s[1024];
  __shared__ float red[256];
  int b = be / EEE;
  int tid = threadIdx.x;
  float acc[4] = {0.f, 0.f, 0.f, 0.f};
  for (int m = 0; m < MMM; m++) {
    float w = emap[(size_t)be * MMM + m];
    if (w != 0.f) {
      const float* mr = mmap + ((size_t)b * MMM + m) * LLL;
      #pragma unroll
      for (int q = 0; q < 4; q++) acc[q] += w * mr[tid + 256 * q];
    }
  }
  red[tid] = acc[0] + acc[1] + acc[2] + acc[3];
  __syncthreads();
  for (int st = 128; st > 0; st >>= 1) {
    if (tid < st) red[tid] += red[tid + st];
    __syncthreads();
  }
  float inv = 1.f / (red[0] + FMIN);
  #pragma unroll
  for (int q = 0; q < 4; q++) em_s[tid + 256 * q] = acc[q] * inv;
  __syncthreads();
  if (tid < 64) {
    int base = 0;
    for (int l0 = 0; l0 < LLL; l0 += 64) {
      float w = em_s[l0 + tid];
      unsigned long long mb = __ballot(w != 0.f);
      int pre = __popcll(mb & ((1ull << tid) - 1ull));
      if (w != 0.f) {
        nzl[be * LLL + base + pre] = l0 + tid;
        nzw[be * LLL + base + pre] = w;
      }
      base += __popcll(mb);
    }
    if (tid == 0) nzc[be] = base;
  }
}

static __device__ void body_entity(int be, const float* __restrict__ ctx,
                                   const float* __restrict__ mmap,
                                   const float* __restrict__ emap,
                                   unsigned short* __restrict__ xb) {
  __shared__ int s_cnt;
  __shared__ int s_l[16];
  __shared__ float s_w[16];
  int b = be / EEE;
  int tid = threadIdx.x;
  float acc[3] = {0.f, 0.f, 0.f};
  float csum = 0.f;
  for (int m = 0; m < MMM; m++) {
    float wm = emap[(size_t)be * MMM + m];
    csum += wm;
    if (wm == 0.f) continue;          // block-uniform
    if (tid == 0) s_cnt = 0;
    __syncthreads();
    const float* mrow = mmap + ((size_t)b * MMM + m) * LLL;
    #pragma unroll
    for (int q = 0; q < 4; q++) {
      int l = tid + 256 * q;
      float w = mrow[l];
      if (w != 0.f) {
        int i = atomicAdd(&s_cnt, 1);
        if (i < 16) { s_l[i] = l; s_w[i] = w; }
      }
    }
    __syncthreads();
    int c = min(s_cnt, 16);
    float dot[3] = {0.f, 0.f, 0.f};
    for (int i = 0; i < c; i++) {
      const float* cr = ctx + ((size_t)b * LLL + s_l[i]) * DDD;
      float w = s_w[i];
      #pragma unroll
      for (int q = 0; q < 3; q++) dot[q] += w * cr[tid + 256 * q];
    }
    #pragma unroll
    for (int q = 0; q < 3; q++) acc[q] += wm * expf(dot[q]);
  }
  bool empty = (csum == 0.f);
  #pragma unroll
  for (int q = 0; q < 3; q++)
    xb[(size_t)be * DDD + tid + 256 * q] = f2bf(empty ? 0.f : logf(acc[q]));
}

static __device__ void body_wprep(int c, const float* __restrict__ Wrel,
                                  unsigned short* __restrict__ tW) {
  __shared__ float w_s[64][98];
  int tid = threadIdx.x;
  for (int idx = tid; idx < 64 * 97; idx += 256) {
    int y = idx / 97, r = idx - y * 97;
    w_s[y][r] = Wrel[(size_t)(c * 64 + y) * RRR + r];
  }
  __syncthreads();
  for (int odx = tid; odx < 8192; odx += 256) {
    int nt = odx >> 10, h = (odx >> 9) & 1, lane = (odx >> 3) & 63, i = odx & 7;
    int y = 32 * h + 8 * (lane >> 4) + i;
    int r = nt * 16 + (lane & 15);
    float v = (r < RRR) ? w_s[y][r] : 0.f;
    tW[(size_t)c * 8192 + odx] = f2h(v);
  }
}

static __device__ void body_transpose(int bx, int by, const float* __restrict__ s,
                                      unsigned short* __restrict__ d, int R, int C) {
  __shared__ float t_s[32][33];
  int c0 = bx * 32, r0 = by * 32;
  int tx = threadIdx.x & 31, ty = threadIdx.x >> 5;
  #pragma unroll
  for (int i = 0; i < 4; i++)
    t_s[ty + i * 8][tx] = s[(size_t)(r0 + ty + i * 8) * C + c0 + tx];
  __syncthreads();
  #pragma unroll
  for (int i = 0; i < 4; i++)
    d[(size_t)(c0 + ty + i * 8) * R + r0 + tx] = f2bf(t_s[tx][ty + i * 8]);
}

__global__ __launch_bounds__(256) void k_prep(PrepArgs a) {
  int bid = blockIdx.x;
  if (bid < NB_EM) {
    body_em(bid, a.emap, a.mmap, a.nzl, a.nzw, a.nzc);
    return;
  }
  bid -= NB_EM;
  if (bid < NB_ENT) {
    body_entity(bid, a.context, a.mmap, a.emap, a.xb);
    return;
  }
  bid -= NB_ENT;
  if (bid < NB_WPREP) {
    body_wprep(bid, a.Wrel, a.tW);
    return;
  }
  bid -= NB_WPREP;
  if (bid < NB_CTX) {
    int bx = bid % 24, by = (bid / 24) % 32, bz = bid / (24 * 32);
    body_transpose(bx, by, a.context + (size_t)bz * LLL * DDD,
                   a.ctxT + (size_t)bz * DDD * LLL, LLL, DDD);
    return;
  }
  bid -= NB_CTX;
  {
    int bx = bid % 24, by = (bid / 24) % 48, bz = bid / (24 * 48);
    int R = (bz < 4) ? DDD : 2 * DDD;
    if (by * 32 < R) body_transpose(bx, by, a.wsrc[bz], a.wdst[bz], R, DDD);
  }
}

// ===========================================================================
// ea[b,e,h,m] = sum_{nz l} w_l * attention[b,h,l,m]  -> bf16
__global__ __launch_bounds__(256) void k_ea(const float* __restrict__ attn,
                                            const int* __restrict__ nzl,
                                            const float* __restrict__ nzw,
                                            const int* __restrict__ nzc,
                                            unsigned short* __restrict__ ea) {
  int e = blockIdx.x, h = blockIdx.y, b = blockIdx.z;
  int be = b * EEE + e;
  int cnt = nzc[be];
  float acc[4] = {0.f, 0.f, 0.f, 0.f};
  for (int i = 0; i < cnt; i++) {
    int l = nzl[be * LLL + i];
    float w = nzw[be * LLL + i];
    const float* ar = attn + (((size_t)b * HHH + h) * LLL + l) * LLL;
    #pragma unroll
    for (int q = 0; q < 4; q++) acc[q] += w * ar[threadIdx.x + 256 * q];
  }
  unsigned short* er = ea + ((size_t)be * HHH + h) * LLL;
  #pragma unroll
  for (int q = 0; q < 4; q++) er[threadIdx.x + 256 * q] = f2bf(acc[q]);
}

// ca[b,p,l] row-normalized -> bf16; also initializes out[bp,:] = b_rel.
__global__ __launch_bounds__(256) void k_ca(const unsigned short* __restrict__ ea,
                                            const int* __restrict__ hts,
                                            unsigned short* __restrict__ cab,
                                            const float* __restrict__ brel,
                                            float* __restrict__ out) {
  int bp = blockIdx.x;            // b*PPP + p
  int b = bp / PPP;
  int hs = hts[bp * 2 + 0], ts = hts[bp * 2 + 1];
  int tid = threadIdx.x;
  if (tid < RRR) out[(size_t)bp * RRR + tid] = brel[tid];
  const unsigned short* eh = ea + (size_t)(b * EEE + hs) * HHH * LLL;
  const unsigned short* et = ea + (size_t)(b * EEE + ts) * HHH * LLL;
  float v[4] = {0.f, 0.f, 0.f, 0.f};
  #pragma unroll
  for (int h = 0; h < HHH; h++) {
    u16x4 hv = *(const u16x4*)&eh[h * LLL + tid * 4];
    u16x4 tv = *(const u16x4*)&et[h * LLL + tid * 4];
    #pragma unroll
    for (int q = 0; q < 4; q++) v[q] += bf2f(hv[q]) * bf2f(tv[q]);
  }
  __shared__ float red[256];
  red[tid] = v[0] + v[1] + v[2] + v[3];
  __syncthreads();
  for (int st = 128; st > 0; st >>= 1) {
    if (tid < st) red[tid] += red[tid + st];
    __syncthreads();
  }
  float inv = 1.f / (red[0] + FMIN);
  u16x4 o;
  #pragma unroll
  for (int q = 0; q < 4; q++) o[q] = f2bf(v[q] * inv);
  *(u16x4*)&cab[(size_t)bp * LLL + tid * 4] = o;
}

// ---------------------------------------------------------------------------
// bf16 MFMA GEMM, 64(M) x 128(N) block, BK=64, 4 waves; wave = 32 rows x 64
// cols (wr=row half, wc=col half). Per ks: 2 A + 4 B fragment reads feed
// 8 MFMAs (was 4:4) — LDS-issue:MFMA ratio 1.8:1 vs 2.4:1, barriers per
// output halved, A panels re-read by 6 (not 12) col-blocks.
// Pipeline: 3-buf LDS, prefetch depth 2, counted vmcnt(6) (6 loads/wave/stage).
struct MGArgs {
  const unsigned short *A, *A2, *BT0, *BT1, *BT2, *BT3;
  float *C0, *C1, *C2;
  const float *nodeW;
  float *nodeWout;
  unsigned short *Cb, *Ch, *Ct;
  const float *bias0, *bias1;
  const float *fni, *fnj, *ebias, *avec;
  float *scores;
  const int *hts;
  int M, K, ldb, koffB;
};

template <int MODE>
__global__ __launch_bounds__(256) void k_mgemm(MGArgs g) {
  __shared__ unsigned short As[3][64 * 64];    // 64 rows x BK64
  __shared__ unsigned short Bs[3][128 * 64];   // 128 cols x BK64
  int tid = threadIdx.x;
  int lane = tid & 63;
  int wv = tid >> 6;
  int l15 = lane & 15, l4 = lane >> 4;
  int wr = wv >> 1, wc = wv & 1;
  int bz = blockIdx.z;

  bool isC = true; int zz = 0;
  if (MODE == 5) {
    isC = bz < 4; zz = bz - 4;
    if (!isC && blockIdx.x >= 2) return;   // FNX has only 2 M-tiles
  }
  int K = g.K, M = g.M, ldb = g.ldb, koffB = g.koffB;
  if (MODE == 5) { K = isC ? LLL : DDD; M = isC ? PPP : NNODE; ldb = K; koffB = 0; }
  int row0 = blockIdx.x * 64, col0 = blockIdx.y * 128;

  const unsigned short* BTp;
  if (MODE == 5) BTp = isC ? g.BT0 + (size_t)bz * DDD * LLL
                           : (zz == 0 ? g.BT1 : (zz == 1 ? g.BT2 : g.BT3));
  else if (MODE == 2) BTp = g.BT0;
  else BTp = bz ? g.BT1 : g.BT0;           // MODE 3/4: wth / wtt

  int sgg = (lane & 7) ^ ((lane >> 3) & 7);
  int srsub = lane >> 3;

  // A: 8 granule-blocks (j = wv*2 + jj); B: 16 (j = wv*4 + jj)
  const unsigned short* gaA[2];
  const unsigned short* gaB[4];
  #pragma unroll
  for (int jj = 0; jj < 2; jj++) {
    int j = wv * 2 + jj;
    int row = j * 8 + srsub;
    int grow = row0 + row; if (grow >= M) grow = M - 1;
    if (MODE == 5) {
      gaA[jj] = isC ? g.A + ((size_t)(bz * PPP) + grow) * LLL + sgg * 8
                    : g.A2 + (size_t)grow * DDD + sgg * 8;
    } else if (MODE == 2) {
      gaA[jj] = (grow < NPAIR) ? g.A + (size_t)grow * DDD + sgg * 8
                               : g.A2 + (size_t)(grow - NPAIR) * DDD + sgg * 8;
    } else {   // MODE 3 (foutb) / MODE 4 (nodesb)
      gaA[jj] = g.A + (size_t)grow * DDD + sgg * 8;
    }
  }
  #pragma unroll
  for (int jj = 0; jj < 4; jj++) {
    int j = wv * 4 + jj;
    int row = j * 8 + srsub;               // 0..127
    gaB[jj] = BTp + (size_t)(col0 + row) * ldb + koffB + sgg * 8;
  }

  auto stage = [&](int buf, int t) {
    int k = t * 64;
    #pragma unroll
    for (int jj = 0; jj < 2; jj++) {
      int j = wv * 2 + jj;
      __builtin_amdgcn_global_load_lds(
          (const __attribute__((address_space(1))) unsigned int*)(gaA[jj] + k),
          (__attribute__((address_space(3))) unsigned int*)&As[buf][j * 512],
          16, 0, 0);
    }
    #pragma unroll
    for (int jj = 0; jj < 4; jj++) {
      int j = wv * 4 + jj;
      __builtin_amdgcn_global_load_lds(
          (const __attribute__((address_space(1))) unsigned int*)(gaB[jj] + k),
          (__attribute__((address_space(3))) unsigned int*)&Bs[buf][j * 512],
          16, 0, 0);
    }
  };

  f32x4 zero = {0.f, 0.f, 0.f, 0.f};
  f32x4 acc[2][4];
  #pragma unroll
  for (int m = 0; m < 2; m++)
    #pragma unroll
    for (int n = 0; n < 4; n++) acc[m][n] = zero;

  int nt = K / 64;
  stage(0, 0);
  stage(1, 1);
  asm volatile("s_waitcnt vmcnt(6)" ::: "memory");   // stage(0) landed
  __builtin_amdgcn_s_barrier();

  int cur = 0;
  for (int t = 0; t < nt; t++) {
    if (t + 2 < nt) {
      int nxt2 = cur - 1; if (nxt2 < 0) nxt2 = 2;    // (t+2)%3
      stage(nxt2, t + 2);
    }
    short8 af[2][2], bfr[2][4];
    #pragma unroll
    for (int ks = 0; ks < 2; ks++) {
      #pragma unroll
      for (int m = 0; m < 2; m++) {
        int row = wr * 32 + m * 16 + l15;
        int phys = (ks * 4 + l4) ^ (row & 7);
        af[ks][m] = *(const short8*)&As[cur][row * 64 + phys * 8];
      }
      #pragma unroll
      for (int n = 0; n < 4; n++) {
        int row = wc * 64 + n * 16 + l15;
        int phys = (ks * 4 + l4) ^ (row & 7);
        bfr[ks][n] = *(const short8*)&Bs[cur][row * 64 + phys * 8];
      }
    }
    #pragma unroll
    for (int ks = 0; ks < 2; ks++)
      #pragma unroll
      for (int m = 0; m < 2; m++)
        #pragma unroll
        for (int n = 0; n < 4; n++)
          acc[m][n] = __builtin_amdgcn_mfma_f32_16x16x32_bf16(af[ks][m], bfr[ks][n], acc[m][n], 0, 0, 0);
    if (t + 1 < nt) {
      if (t + 2 < nt) asm volatile("s_waitcnt vmcnt(6)" ::: "memory");
      else            asm volatile("s_waitcnt vmcnt(0)" ::: "memory");
      __builtin_amdgcn_s_barrier();
    }
    cur += 1; if (cur == 3) cur = 0;
  }

  // MODE 2: score_s[row 0..63][head-in-block 0..1]; one head per wave (wc).
  float* score_s = (float*)&As[0][0];
  if (MODE == 2) {
    if (tid < 128) score_s[tid] = 0.f;
    __syncthreads();
  }

  float sp[2][4] = {};
  #pragma unroll
  for (int m = 0; m < 2; m++) {
    int rbase = row0 + wr * 32 + m * 16 + l4 * 4;
    #pragma unroll
    for (int n = 0; n < 4; n++) {
      int col = col0 + wc * 64 + n * 16 + l15;
      #pragma unroll
      for (int q = 0; q < 4; q++) {
        int r = rbase + q;
        if (r >= M) continue;
        float v = acc[m][n][q];
        if (MODE == 5) {
          if (isC) {
            size_t grow = (size_t)bz * PPP + r;
            int h0 = g.hts[grow * 2 + 0], h1 = g.hts[grow * 2 + 1];
            float mk = (h0 + h1 != 0) ? 1.f : 0.f;
            g.Cb[grow * DDD + col] = f2bf(v * mk);
          } else {
            float* C = zz == 0 ? g.C0 : (zz == 1 ? g.C1 : g.C2);
            C[(size_t)r * DDD + col] = v;
          }
        } else if (MODE == 2) {
          int srcn, dstn;
          if (r < NPAIR) {
            int bb = r / PPP;
            srcn = bb * EEE + g.hts[r * 2 + 0];
            dstn = bb * EEE + g.hts[r * 2 + 1];
          } else {
            srcn = dstn = r - NPAIR;
          }
          float vv = v + g.fni[(size_t)srcn * DDD + col] +
                     g.fnj[(size_t)dstn * DDD + col] + g.ebias[col];
          g.Cb[(size_t)r * DDD + col] = f2bf(vv);
          float lrv = vv > 0.f ? vv : 0.2f * vv;
          sp[m][q] += lrv * g.avec[col];
        } else if (MODE == 4) {
          g.nodeWout[((size_t)bz * NNODE + r) * DDD + col] = v;
        } else {   // MODE 3
          int bb = r / PPP;
          int node = bb * EEE + g.hts[r * 2 + bz];
          const float* bias = bz ? g.bias1 : g.bias0;
          float v2 = v + g.nodeW[((size_t)bz * NNODE + node) * DDD + col] + bias[col];
          unsigned short* C = bz ? g.Ct : g.Ch;
          C[(size_t)r * DDD + col] = f2h(tanhf(v2));
        }
      }
    }
  }

  if (MODE == 2) {
    #pragma unroll
    for (int m = 0; m < 2; m++) {
      #pragma unroll
      for (int q = 0; q < 4; q++) {
        float s = sp[m][q];
        s += __shfl_xor(s, 1);
        s += __shfl_xor(s, 2);
        s += __shfl_xor(s, 4);
        s += __shfl_xor(s, 8);
        int r = row0 + wr * 32 + m * 16 + l4 * 4 + q;
        if (l15 == 0 && r < M) atomicAdd(&score_s[(r - row0) * 2 + wc], s);
      }
    }
    __syncthreads();
    if (tid < 128) {
      int r = row0 + (tid >> 1);
      int h = blockIdx.y * 2 + (tid & 1);
      if (r < M) g.scores[r * HHH + h] = score_s[tid];
    }
  }
}

// ---------------------------------------------------------------------------
// per-node edge softmax over in-edges + message aggregation -> nodes bf16
#define ECAP 256
__global__ __launch_bounds__(256) void k_agg(const float* __restrict__ scores,
                                             const float* __restrict__ fnode,
                                             const int* __restrict__ hts,
                                             unsigned short* __restrict__ nodesb) {
  __shared__ int cnt;
  __shared__ int elist[ECAP], slist[ECAP];
  __shared__ float smax[HHH], ssum[HHH];
  __shared__ float alpha[ECAP * HHH];
  int n = blockIdx.x, tid = threadIdx.x;
  if (tid == 0) cnt = 0;
  __syncthreads();
  for (int e = tid; e < NEDGE; e += 256) {
    int srcn, dstn;
    if (e < NPAIR) {
      int b = e / PPP;
      srcn = b * EEE + hts[e * 2 + 0];
      dstn = b * EEE + hts[e * 2 + 1];
    } else {
      srcn = dstn = e - NPAIR;
    }
    if (dstn == n) {
      int i = atomicAdd(&cnt, 1);
      if (i < ECAP) { elist[i] = e; slist[i] = srcn; }
    }
  }
  __syncthreads();
  int c = min(cnt, ECAP);
  if (tid < HHH) {
    float m = -1e30f;
    for (int i = 0; i < c; i++) m = fmaxf(m, scores[elist[i] * HHH + tid]);
    smax[tid] = m;
    float s = 0.f;
    for (int i = 0; i < c; i++) s += expf(scores[elist[i] * HHH + tid] - m);
    ssum[tid] = s;
  }
  __syncthreads();
  for (int t = tid; t < c * HHH; t += 256) {
    int i = t / HHH, h = t - i * HHH;
    alpha[t] = expf(scores[elist[i] * HHH + h] - smax[h]) / ssum[h];
  }
  __syncthreads();
  for (int j = tid; j < DDD; j += 256) {
    int h = j >> 6;
    float acc = 0.f;
    for (int i = 0; i < c; i++)
      acc += alpha[i * HHH + h] * fnode[(size_t)slist[i] * DDD + j];
    nodesb[(size_t)n * DDD + j] = f2bf(acc);
  }
}

// ---------------------------------------------------------------------------
// Group-bilinear MFMA GEMM, barrier-free, fp16 island (round-13 version).
__global__ __launch_bounds__(256) void k_bilinear_mfma(
    const unsigned short* __restrict__ newh, const unsigned short* __restrict__ newt,
    const unsigned short* __restrict__ tW, float* __restrict__ out) {
  __shared__ unsigned short a_s[64][64];   // [x][p] fp16
  int tid = threadIdx.x;
  int lane = tid & 63;
  int wv = tid >> 6;
  int l15 = lane & 15, l4 = lane >> 4;
  int bid = blockIdx.x;
  int kg = bid / 55, pt = bid - kg * 55;
  bool use1 = ((wv + 4) * 16) < RRR;       // false only for wv==3

  {
    int pl = tid >> 2, xq = (tid & 3) * 16;
    int prow = pt * 64 + pl; if (prow >= NPAIR) prow = NPAIR - 1;
    const unsigned short* src = newh + (size_t)prow * DDD + kg * 64 + xq;
    #pragma unroll
    for (int half16 = 0; half16 < 2; half16++) {
      u16x4 v0 = *(const u16x4*)(src + half16 * 8);
      u16x4 v1 = *(const u16x4*)(src + half16 * 8 + 4);
      #pragma unroll
      for (int i = 0; i < 4; i++) {
        a_s[xq + half16 * 8 + i][pl] = v0[i];
        a_s[xq + half16 * 8 + 4 + i][pl] = v1[i];
      }
    }
  }

  f16x8 bfrag[4][2];
  #pragma unroll
  for (int t = 0; t < 4; t++) {
    int prow = pt * 64 + t * 16 + l15; if (prow >= NPAIR) prow = NPAIR - 1;
    const unsigned short* src = newt + (size_t)prow * DDD + kg * 64 + 8 * l4;
    #pragma unroll
    for (int h = 0; h < 2; h++)
      bfrag[t][h] = __builtin_bit_cast(f16x8, *(const uint4*)(src + h * 32));
  }
  __syncthreads();   // a_s ready; no further barriers

  f32x4 zero = {0.f, 0.f, 0.f, 0.f};
  f32x4 acc[4][2];
  #pragma unroll
  for (int t = 0; t < 4; t++) { acc[t][0] = zero; acc[t][1] = zero; }

  const unsigned short* wp = tW + (size_t)(kg * 64) * 8192 + lane * 8;
  int o00 = (wv * 2 + 0) << 9;
  int o01 = (wv * 2 + 1) << 9;
  int o10 = ((wv + 4) * 2 + 0) << 9;
  int o11 = ((wv + 4) * 2 + 1) << 9;

  auto loadw = [&](uint4* wf, int x) {
    const unsigned short* p = wp + (size_t)x * 8192;
    wf[0] = *(const uint4*)(p + o00);
    wf[1] = *(const uint4*)(p + o01);
    if (use1) {
      wf[2] = *(const uint4*)(p + o10);
      wf[3] = *(const uint4*)(p + o11);
    }
  };
  auto step = [&](const uint4* wf, int x) {
    f16x8 a8[4];
    #pragma unroll
    for (int t = 0; t < 4; t++) {
      unsigned int av = a_s[x][t * 16 + l15];
      unsigned int aw = (av << 16) | av;
      uint4 ab = {aw, aw, aw, aw};
      a8[t] = __builtin_bit_cast(f16x8, ab);
    }
    #pragma unroll
    for (int h = 0; h < 2; h++) {
      f16x8 w0 = __builtin_bit_cast(f16x8, wf[h]);
      f16x8 w1 = __builtin_bit_cast(f16x8, wf[2 + h]);
      #pragma unroll
      for (int t = 0; t < 4; t++) {
        f16x8 gv = a8[t] * bfrag[t][h];     // v_pk_mul_f16
        acc[t][0] = __builtin_amdgcn_mfma_f32_16x16x32_f16(gv, w0, acc[t][0], 0, 0, 0);
        if (use1)
          acc[t][1] = __builtin_amdgcn_mfma_f32_16x16x32_f16(gv, w1, acc[t][1], 0, 0, 0);
      }
    }
  };

  uint4 wa[4], wb[4];
  loadw(wa, 0);
  for (int xx = 0; xx < 64; xx += 2) {
    loadw(wb, xx + 1);
    step(wa, xx);
    if (xx + 2 < 64) loadw(wa, xx + 2);
    step(wb, xx + 1);
  }

  #pragma unroll
  for (int n = 0; n < 2; n++) {
    int r = (wv + 4 * n) * 16 + l15;
    if (r >= RRR) continue;
    #pragma unroll
    for (int t = 0; t < 4; t++) {
      int pbase = pt * 64 + t * 16 + l4 * 4;
      #pragma unroll
      for (int q = 0; q < 4; q++) {
        int p = pbase + q;
        if (p < NPAIR) atomicAdd(&out[(size_t)p * RRR + r], acc[t][n][q]);
      }
    }
  }
}

// ---------------------------------------------------------------------------
extern "C" void kernel_launch(void* const* d_in, const int* in_sizes, int n_in,
                              void* d_out, int out_size, void* d_ws, size_t ws_size,
                              hipStream_t stream) {
  const float* context   = (const float*)d_in[0];
  const float* attention = (const float*)d_in[1];
  const float* mmap      = (const float*)d_in[2];
  const float* emap      = (const float*)d_in[3];
  const int*   hts       = (const int*)d_in[4];
  const float* W_h       = (const float*)d_in[5];
  const float* b_h       = (const float*)d_in[6];
  const float* W_t       = (const float*)d_in[7];
  const float* b_t       = (const float*)d_in[8];
  const float* W_node    = (const float*)d_in[9];
  const float* W_ni      = (const float*)d_in[10];
  const float* W_nj      = (const float*)d_in[11];
  const float* W_fij     = (const float*)d_in[12];
  const float* egat_bias = (const float*)d_in[13];
  const float* attn_vec  = (const float*)d_in[14];
  const float* W_rel     = (const float*)d_in[15];
  const float* b_rel     = (const float*)d_in[16];
  float* out = (float*)d_out;

  float* ws = (float*)d_ws;
  size_t o = 0;
  auto alloc = [&](size_t n) { size_t r = o; o += (n + 63) & ~(size_t)63; return r; };
  auto halloc = [&](size_t nshorts) { return alloc((nshorts + 1) / 2); };  // 16-bit buffers
  size_t o_xb      = halloc((size_t)NNODE * DDD);
  size_t o_ea      = halloc((size_t)BB * EEE * HHH * LLL);
  size_t o_cab     = halloc((size_t)NPAIR * LLL);
  size_t o_ctxT    = halloc((size_t)BB * DDD * LLL);
  size_t o_wtni    = halloc((size_t)DDD * DDD);
  size_t o_wtnj    = halloc((size_t)DDD * DDD);
  size_t o_wtnode  = halloc((size_t)DDD * DDD);
  size_t o_wtfij   = halloc((size_t)DDD * DDD);
  size_t o_wth     = halloc((size_t)DDD * 2 * DDD);
  size_t o_wtt     = halloc((size_t)DDD * 2 * DDD);
  size_t o_cinfob  = halloc((size_t)NPAIR * DDD);
  size_t o_fni     = alloc((size_t)NNODE * DDD);
  size_t o_fnj     = alloc((size_t)NNODE * DDD);
  size_t o_fnode   = alloc((size_t)NNODE * DDD);
  size_t o_foutb   = halloc((size_t)NEDGE * DDD);
  size_t o_scores  = alloc((size_t)NEDGE * HHH);
  size_t o_nodesb  = halloc((size_t)NNODE * DDD);
  size_t o_nodew   = alloc((size_t)2 * NNODE * DDD);  // fp32 [z][node][col]
  size_t o_newh    = halloc((size_t)NPAIR * DDD);     // fp16
  size_t o_newt    = halloc((size_t)NPAIR * DDD);     // fp16
  size_t o_nzl     = alloc((size_t)BB * EEE * LLL);
  size_t o_nzw     = alloc((size_t)BB * EEE * LLL);
  size_t o_nzc     = alloc(128);
  size_t o_tw      = halloc((size_t)768 * 8192);      // 12.6 MB fragment-major fp16
  (void)ws_size; // ~66 MB used

  unsigned short* xb     = (unsigned short*)(ws + o_xb);
  unsigned short* ea     = (unsigned short*)(ws + o_ea);
  unsigned short* cab    = (unsigned short*)(ws + o_cab);
  unsigned short* ctxT   = (unsigned short*)(ws + o_ctxT);
  unsigned short* wtni   = (unsigned short*)(ws + o_wtni);
  unsigned short* wtnj   = (unsigned short*)(ws + o_wtnj);
  unsigned short* wtnode = (unsigned short*)(ws + o_wtnode);
  unsigned short* wtfij  = (unsigned short*)(ws + o_wtfij);
  unsigned short* wth    = (unsigned short*)(ws + o_wth);
  unsigned short* wtt    = (unsigned short*)(ws + o_wtt);
  unsigned short* cinfob = (unsigned short*)(ws + o_cinfob);
  float* fni     = ws + o_fni;
  float* fnj     = ws + o_fnj;
  float* fnode   = ws + o_fnode;
  unsigned short* foutb  = (unsigned short*)(ws + o_foutb);
  float* scores  = ws + o_scores;
  unsigned short* nodesb = (unsigned short*)(ws + o_nodesb);
  float* nodeW   = ws + o_nodew;
  unsigned short* newh   = (unsigned short*)(ws + o_newh);
  unsigned short* newt   = (unsigned short*)(ws + o_newt);
  int*   nzl     = (int*)(ws + o_nzl);
  float* nzw     = ws + o_nzw;
  int*   nzc     = (int*)(ws + o_nzc);
  unsigned short* tW = (unsigned short*)(ws + o_tw);

  // ---- fused prep (em + entity FIRST, then wprep + ctx + 6 W transposes) ----
  PrepArgs pa;
  pa.Wrel = W_rel; pa.context = context; pa.mmap = mmap; pa.emap = emap;
  pa.wsrc[0] = W_ni;  pa.wdst[0] = wtni;
  pa.wsrc[1] = W_nj;  pa.wdst[1] = wtnj;
  pa.wsrc[2] = W_node; pa.wdst[2] = wtnode;
  pa.wsrc[3] = W_fij; pa.wdst[3] = wtfij;
  pa.wsrc[4] = W_h;   pa.wdst[4] = wth;
  pa.wsrc[5] = W_t;   pa.wdst[5] = wtt;
  pa.tW = tW; pa.ctxT = ctxT; pa.xb = xb;
  pa.nzl = nzl; pa.nzw = nzw; pa.nzc = nzc;
  k_prep<<<NB_EM + NB_ENT + NB_WPREP + NB_CTX + NB_WT, 256, 0, stream>>>(pa);

  k_ea<<<dim3(EEE, HHH, BB), 256, 0, stream>>>(attention, nzl, nzw, nzc, ea);
  k_ca<<<BB * PPP, 256, 0, stream>>>(ea, hts, cab, b_rel, out);

  // ---- MODE 5: CINFO (z<4) + FNX (z=4..6) in one dispatch (N-tiles of 128) ----
  MGArgs g5 = {};
  g5.A = cab; g5.A2 = xb;
  g5.BT0 = ctxT; g5.BT1 = wtni; g5.BT2 = wtnj; g5.BT3 = wtnode;
  g5.Cb = cinfob; g5.C0 = fni; g5.C1 = fnj; g5.C2 = fnode;
  g5.hts = hts;
  k_mgemm<5><<<dim3(14, 6, 7), 256, 0, stream>>>(g5);

  // ---- MODE 2: FFIJ + fused scores ----
  MGArgs g2 = {};
  g2.A = cinfob; g2.A2 = xb; g2.BT0 = wtfij; g2.Cb = foutb;
  g2.fni = fni; g2.fnj = fnj; g2.ebias = egat_bias; g2.avec = attn_vec;
  g2.scores = scores; g2.hts = hts;
  g2.M = NEDGE; g2.K = DDD; g2.ldb = DDD; g2.koffB = 0;
  k_mgemm<2><<<dim3(57, 6, 1), 256, 0, stream>>>(g2);

  k_agg<<<NNODE, 256, 0, stream>>>(scores, fnode, hts, nodesb);

  // ---- MODE 4: nodeW[z][node] = nodesb @ W_{h,t}[:768] ----
  MGArgs g4 = {};
  g4.A = nodesb; g4.BT0 = wth; g4.BT1 = wtt; g4.nodeWout = nodeW;
  g4.M = NNODE; g4.K = DDD; g4.ldb = 2 * DDD; g4.koffB = 0;
  k_mgemm<4><<<dim3(2, 6, 2), 256, 0, stream>>>(g4);

  // ---- MODE 3: NEWHT (K=768 over foutb; nodeW gathered in epilogue) ----
  MGArgs g3 = {};
  g3.A = foutb; g3.BT0 = wth; g3.BT1 = wtt; g3.nodeW = nodeW;
  g3.bias0 = b_h; g3.bias1 = b_t; g3.Ch = newh; g3.Ct = newt; g3.hts = hts;
  g3.M = NPAIR; g3.K = DDD; g3.ldb = 2 * DDD; g3.koffB = DDD;
  k_mgemm<3><<<dim3(55, 6, 2), 256, 0, stream>>>(g3);

  // ---- bilinear classifier (fp16 island; out pre-initialized in k_ca) ----
  k_bilinear_mfma<<<55 * 12, 256, 0, stream>>>(newh, newt, tW, out);
}

// Round 15
// 204.885 us; speedup vs baseline: 1.1386x; 1.1386x over previous
//
#include <hip/hip_runtime.h>
#include <math.h>

// Problem constants
#define BB 4
#define LLL 1024
#define DDD 768
#define HHH 12
#define EEE 30
#define MMM 60
#define PPP 870
#define RRR 97
#define NNODE 120   // B*E
#define NPAIR 3480  // B*P
#define NEDGE 3600  // NPAIR + NNODE self loops
#define FMIN 1e-10f

typedef __attribute__((ext_vector_type(8))) __bf16 bf16x8;
typedef __attribute__((ext_vector_type(8))) short short8;
typedef __attribute__((ext_vector_type(8))) _Float16 f16x8;
typedef __attribute__((ext_vector_type(4))) float f32x4;
typedef __attribute__((ext_vector_type(4))) unsigned short u16x4;

static __device__ __forceinline__ unsigned short f2bf(float v) {
  return __builtin_bit_cast(unsigned short, (__bf16)v);
}
static __device__ __forceinline__ unsigned short f2h(float v) {
  return __builtin_bit_cast(unsigned short, (_Float16)v);
}
static __device__ __forceinline__ float bf2f(unsigned short u) {
  unsigned int x = ((unsigned int)u) << 16;
  return __builtin_bit_cast(float, x);
}

// ===========================================================================
// FUSED PREP KERNEL. LONG blocks (em, entity) first so they hide under the
// ~10k short transpose blocks (round-13 verified layout).
// ===========================================================================
struct PrepArgs {
  const float *Wrel, *context, *mmap, *emap;
  const float *wsrc[6];
  unsigned short *tW, *ctxT, *xb;
  unsigned short *wdst[6];
  int *nzl, *nzc;
  float *nzw;
};

#define NB_EM    NNODE
#define NB_ENT   NNODE
#define NB_WPREP 768
#define NB_CTX   (24 * 32 * BB)
#define NB_WT    (24 * 48 * 6)

static __device__ void body_em(int be, const float* __restrict__ emap,
                               const float* __restrict__ mmap,
                               int* __restrict__ nzl, float* __restrict__ nzw,
                               int* __restrict__ nzc) {
  __shared__ float em_s[1024];
  __shared__ float red[256];
  int b = be / EEE;
  int tid = threadIdx.x;
  float acc[4] = {0.f, 0.f, 0.f, 0.f};
  for (int m = 0; m < MMM; m++) {
    float w = emap[(size_t)be * MMM + m];
    if (w != 0.f) {
      const float* mr = mmap + ((size_t)b * MMM + m) * LLL;
      #pragma unroll
      for (int q = 0; q < 4; q++) acc[q] += w * mr[tid + 256 * q];
    }
  }
  red[tid] = acc[0] + acc[1] + acc[2] + acc[3];
  __syncthreads();
  for (int st = 128; st > 0; st >>= 1) {
    if (tid < st) red[tid] += red[tid + st];
    __syncthreads();
  }
  float inv = 1.f / (red[0] + FMIN);
  #pragma unroll
  for (int q = 0; q < 4; q++) em_s[tid + 256 * q] = acc[q] * inv;
  __syncthreads();
  if (tid < 64) {
    int base = 0;
    for (int l0 = 0; l0 < LLL; l0 += 64) {
      float w = em_s[l0 + tid];
      unsigned long long mb = __ballot(w != 0.f);
      int pre = __popcll(mb & ((1ull << tid) - 1ull));
      if (w != 0.f) {
        nzl[be * LLL + base + pre] = l0 + tid;
        nzw[be * LLL + base + pre] = w;
      }
      base += __popcll(mb);
    }
    if (tid == 0) nzc[be] = base;
  }
}

static __device__ void body_entity(int be, const float* __restrict__ ctx,
                                   const float* __restrict__ mmap,
                                   const float* __restrict__ emap,
                                   unsigned short* __restrict__ xb) {
  __shared__ int s_cnt;
  __shared__ int s_l[16];
  __shared__ float s_w[16];
  int b = be / EEE;
  int tid = threadIdx.x;
  float acc[3] = {0.f, 0.f, 0.f};
  float csum = 0.f;
  for (int m = 0; m < MMM; m++) {
    float wm = emap[(size_t)be * MMM + m];
    csum += wm;
    if (wm == 0.f) continue;          // block-uniform
    if (tid == 0) s_cnt = 0;
    __syncthreads();
    const float* mrow = mmap + ((size_t)b * MMM + m) * LLL;
    #pragma unroll
    for (int q = 0; q < 4; q++) {
      int l = tid + 256 * q;
      float w = mrow[l];
      if (w != 0.f) {
        int i = atomicAdd(&s_cnt, 1);
        if (i < 16) { s_l[i] = l; s_w[i] = w; }
      }
    }
    __syncthreads();
    int c = min(s_cnt, 16);
    float dot[3] = {0.f, 0.f, 0.f};
    for (int i = 0; i < c; i++) {
      const float* cr = ctx + ((size_t)b * LLL + s_l[i]) * DDD;
      float w = s_w[i];
      #pragma unroll
      for (int q = 0; q < 3; q++) dot[q] += w * cr[tid + 256 * q];
    }
    #pragma unroll
    for (int q = 0; q < 3; q++) acc[q] += wm * expf(dot[q]);
  }
  bool empty = (csum == 0.f);
  #pragma unroll
  for (int q = 0; q < 3; q++)
    xb[(size_t)be * DDD + tid + 256 * q] = f2bf(empty ? 0.f : logf(acc[q]));
}

static __device__ void body_wprep(int c, const float* __restrict__ Wrel,
                                  unsigned short* __restrict__ tW) {
  __shared__ float w_s[64][98];
  int tid = threadIdx.x;
  for (int idx = tid; idx < 64 * 97; idx += 256) {
    int y = idx / 97, r = idx - y * 97;
    w_s[y][r] = Wrel[(size_t)(c * 64 + y) * RRR + r];
  }
  __syncthreads();
  for (int odx = tid; odx < 8192; odx += 256) {
    int nt = odx >> 10, h = (odx >> 9) & 1, lane = (odx >> 3) & 63, i = odx & 7;
    int y = 32 * h + 8 * (lane >> 4) + i;
    int r = nt * 16 + (lane & 15);
    float v = (r < RRR) ? w_s[y][r] : 0.f;
    tW[(size_t)c * 8192 + odx] = f2h(v);
  }
}

static __device__ void body_transpose(int bx, int by, const float* __restrict__ s,
                                      unsigned short* __restrict__ d, int R, int C) {
  __shared__ float t_s[32][33];
  int c0 = bx * 32, r0 = by * 32;
  int tx = threadIdx.x & 31, ty = threadIdx.x >> 5;
  #pragma unroll
  for (int i = 0; i < 4; i++)
    t_s[ty + i * 8][tx] = s[(size_t)(r0 + ty + i * 8) * C + c0 + tx];
  __syncthreads();
  #pragma unroll
  for (int i = 0; i < 4; i++)
    d[(size_t)(c0 + ty + i * 8) * R + r0 + tx] = f2bf(t_s[tx][ty + i * 8]);
}

__global__ __launch_bounds__(256) void k_prep(PrepArgs a) {
  int bid = blockIdx.x;
  if (bid < NB_EM) {
    body_em(bid, a.emap, a.mmap, a.nzl, a.nzw, a.nzc);
    return;
  }
  bid -= NB_EM;
  if (bid < NB_ENT) {
    body_entity(bid, a.context, a.mmap, a.emap, a.xb);
    return;
  }
  bid -= NB_ENT;
  if (bid < NB_WPREP) {
    body_wprep(bid, a.Wrel, a.tW);
    return;
  }
  bid -= NB_WPREP;
  if (bid < NB_CTX) {
    int bx = bid % 24, by = (bid / 24) % 32, bz = bid / (24 * 32);
    body_transpose(bx, by, a.context + (size_t)bz * LLL * DDD,
                   a.ctxT + (size_t)bz * DDD * LLL, LLL, DDD);
    return;
  }
  bid -= NB_CTX;
  {
    int bx = bid % 24, by = (bid / 24) % 48, bz = bid / (24 * 48);
    int R = (bz < 4) ? DDD : 2 * DDD;
    if (by * 32 < R) body_transpose(bx, by, a.wsrc[bz], a.wdst[bz], R, DDD);
  }
}

// ===========================================================================
// ea[b,e,h,m] = sum_{nz l} w_l * attention[b,h,l,m]  -> bf16
__global__ __launch_bounds__(256) void k_ea(const float* __restrict__ attn,
                                            const int* __restrict__ nzl,
                                            const float* __restrict__ nzw,
                                            const int* __restrict__ nzc,
                                            unsigned short* __restrict__ ea) {
  int e = blockIdx.x, h = blockIdx.y, b = blockIdx.z;
  int be = b * EEE + e;
  int cnt = nzc[be];
  float acc[4] = {0.f, 0.f, 0.f, 0.f};
  for (int i = 0; i < cnt; i++) {
    int l = nzl[be * LLL + i];
    float w = nzw[be * LLL + i];
    const float* ar = attn + (((size_t)b * HHH + h) * LLL + l) * LLL;
    #pragma unroll
    for (int q = 0; q < 4; q++) acc[q] += w * ar[threadIdx.x + 256 * q];
  }
  unsigned short* er = ea + ((size_t)be * HHH + h) * LLL;
  #pragma unroll
  for (int q = 0; q < 4; q++) er[threadIdx.x + 256 * q] = f2bf(acc[q]);
}

// ca[b,p,l] row-normalized -> bf16; also initializes out[bp,:] = b_rel.
__global__ __launch_bounds__(256) void k_ca(const unsigned short* __restrict__ ea,
                                            const int* __restrict__ hts,
                                            unsigned short* __restrict__ cab,
                                            const float* __restrict__ brel,
                                            float* __restrict__ out) {
  int bp = blockIdx.x;            // b*PPP + p
  int b = bp / PPP;
  int hs = hts[bp * 2 + 0], ts = hts[bp * 2 + 1];
  int tid = threadIdx.x;
  if (tid < RRR) out[(size_t)bp * RRR + tid] = brel[tid];
  const unsigned short* eh = ea + (size_t)(b * EEE + hs) * HHH * LLL;
  const unsigned short* et = ea + (size_t)(b * EEE + ts) * HHH * LLL;
  float v[4] = {0.f, 0.f, 0.f, 0.f};
  #pragma unroll
  for (int h = 0; h < HHH; h++) {
    u16x4 hv = *(const u16x4*)&eh[h * LLL + tid * 4];
    u16x4 tv = *(const u16x4*)&et[h * LLL + tid * 4];
    #pragma unroll
    for (int q = 0; q < 4; q++) v[q] += bf2f(hv[q]) * bf2f(tv[q]);
  }
  __shared__ float red[256];
  red[tid] = v[0] + v[1] + v[2] + v[3];
  __syncthreads();
  for (int st = 128; st > 0; st >>= 1) {
    if (tid < st) red[tid] += red[tid + st];
    __syncthreads();
  }
  float inv = 1.f / (red[0] + FMIN);
  u16x4 o;
  #pragma unroll
  for (int q = 0; q < 4; q++) o[q] = f2bf(v[q] * inv);
  *(u16x4*)&cab[(size_t)bp * LLL + tid * 4] = o;
}

// ---------------------------------------------------------------------------
// bf16 MFMA GEMM, 64x64 tile, BK=64, 4 waves (2x2), pipelined (3-buf, vmcnt(4)).
struct MGArgs {
  const unsigned short *A, *A2, *BT0, *BT1, *BT2, *BT3;
  float *C0, *C1, *C2;
  const float *nodeW;
  float *nodeWout;
  unsigned short *Cb, *Ch, *Ct;
  const float *bias0, *bias1;
  const float *fni, *fnj, *ebias, *avec;
  float *scores;
  const int *hts;
  int M, K, ldb, koffB;
};

template <int MODE>
__global__ __launch_bounds__(256) void k_mgemm(MGArgs g) {
  __shared__ unsigned short As[3][64 * 64];
  __shared__ unsigned short Bs[3][64 * 64];
  int tid = threadIdx.x;
  int lane = tid & 63;
  int wv = tid >> 6;
  int l15 = lane & 15, l4 = lane >> 4;
  int wr = wv >> 1, wc = wv & 1;
  int bz = blockIdx.z;

  bool isC = true; int zz = 0;
  if (MODE == 5) {
    isC = bz < 4; zz = bz - 4;
    if (!isC && blockIdx.x >= 2) return;   // FNX has only 2 M-tiles
  }
  int K = g.K, M = g.M, ldb = g.ldb, koffB = g.koffB;
  if (MODE == 5) { K = isC ? LLL : DDD; M = isC ? PPP : NNODE; ldb = K; koffB = 0; }
  int row0 = blockIdx.x * 64, col0 = blockIdx.y * 64;

  const unsigned short* BTp;
  if (MODE == 5) BTp = isC ? g.BT0 + (size_t)bz * DDD * LLL
                           : (zz == 0 ? g.BT1 : (zz == 1 ? g.BT2 : g.BT3));
  else if (MODE == 2) BTp = g.BT0;
  else BTp = bz ? g.BT1 : g.BT0;           // MODE 3/4: wth / wtt

  int sgg = (lane & 7) ^ ((lane >> 3) & 7);
  int srsub = lane >> 3;

  const unsigned short* gaA[2];
  const unsigned short* gaB[2];
  #pragma unroll
  for (int jj = 0; jj < 2; jj++) {
    int j = wv * 2 + jj;
    int row = j * 8 + srsub;
    int grow = row0 + row; if (grow >= M) grow = M - 1;
    if (MODE == 5) {
      gaA[jj] = isC ? g.A + ((size_t)(bz * PPP) + grow) * LLL + sgg * 8
                    : g.A2 + (size_t)grow * DDD + sgg * 8;
    } else if (MODE == 2) {
      gaA[jj] = (grow < NPAIR) ? g.A + (size_t)grow * DDD + sgg * 8
                               : g.A2 + (size_t)(grow - NPAIR) * DDD + sgg * 8;
    } else {   // MODE 3 (foutb) / MODE 4 (nodesb)
      gaA[jj] = g.A + (size_t)grow * DDD + sgg * 8;
    }
    gaB[jj] = BTp + (size_t)(col0 + row) * ldb + koffB + sgg * 8;
  }

  auto stage = [&](int buf, int t) {
    int k = t * 64;
    #pragma unroll
    for (int jj = 0; jj < 2; jj++) {
      int j = wv * 2 + jj;
      __builtin_amdgcn_global_load_lds(
          (const __attribute__((address_space(1))) unsigned int*)(gaA[jj] + k),
          (__attribute__((address_space(3))) unsigned int*)&As[buf][j * 512],
          16, 0, 0);
      __builtin_amdgcn_global_load_lds(
          (const __attribute__((address_space(1))) unsigned int*)(gaB[jj] + k),
          (__attribute__((address_space(3))) unsigned int*)&Bs[buf][j * 512],
          16, 0, 0);
    }
  };

  f32x4 zero = {0.f, 0.f, 0.f, 0.f};
  f32x4 acc[2][2];
  #pragma unroll
  for (int m = 0; m < 2; m++)
    #pragma unroll
    for (int n = 0; n < 2; n++) acc[m][n] = zero;

  int nt = K / 64;
  stage(0, 0);
  stage(1, 1);
  asm volatile("s_waitcnt vmcnt(4)" ::: "memory");   // stage(0) landed
  __builtin_amdgcn_s_barrier();

  int cur = 0;
  for (int t = 0; t < nt; t++) {
    if (t + 2 < nt) {
      int nxt2 = cur - 1; if (nxt2 < 0) nxt2 = 2;    // (t+2)%3
      stage(nxt2, t + 2);
    }
    short8 af[2][2], bfr[2][2];
    #pragma unroll
    for (int ks = 0; ks < 2; ks++) {
      #pragma unroll
      for (int m = 0; m < 2; m++) {
        int row = wr * 32 + m * 16 + l15;
        int phys = (ks * 4 + l4) ^ (row & 7);
        af[ks][m] = *(const short8*)&As[cur][row * 64 + phys * 8];
      }
      #pragma unroll
      for (int n = 0; n < 2; n++) {
        int row = wc * 32 + n * 16 + l15;
        int phys = (ks * 4 + l4) ^ (row & 7);
        bfr[ks][n] = *(const short8*)&Bs[cur][row * 64 + phys * 8];
      }
    }
    #pragma unroll
    for (int ks = 0; ks < 2; ks++)
      #pragma unroll
      for (int m = 0; m < 2; m++)
        #pragma unroll
        for (int n = 0; n < 2; n++)
          acc[m][n] = __builtin_amdgcn_mfma_f32_16x16x32_bf16(af[ks][m], bfr[ks][n], acc[m][n], 0, 0, 0);
    if (t + 1 < nt) {
      if (t + 2 < nt) asm volatile("s_waitcnt vmcnt(4)" ::: "memory");
      else            asm volatile("s_waitcnt vmcnt(0)" ::: "memory");
      __builtin_amdgcn_s_barrier();
    }
    cur += 1; if (cur == 3) cur = 0;
  }

  float* score_s = (float*)&As[0][0];
  if (MODE == 2) {
    if (tid < 64) score_s[tid] = 0.f;
    __syncthreads();
  }

  float sp[2][4] = {};
  #pragma unroll
  for (int m = 0; m < 2; m++) {
    int rbase = row0 + wr * 32 + m * 16 + l4 * 4;
    #pragma unroll
    for (int n = 0; n < 2; n++) {
      int col = col0 + wc * 32 + n * 16 + l15;
      #pragma unroll
      for (int q = 0; q < 4; q++) {
        int r = rbase + q;
        if (r >= M) continue;
        float v = acc[m][n][q];
        if (MODE == 5) {
          if (isC) {
            size_t grow = (size_t)bz * PPP + r;
            int h0 = g.hts[grow * 2 + 0], h1 = g.hts[grow * 2 + 1];
            float mk = (h0 + h1 != 0) ? 1.f : 0.f;
            g.Cb[grow * DDD + col] = f2bf(v * mk);
          } else {
            float* C = zz == 0 ? g.C0 : (zz == 1 ? g.C1 : g.C2);
            C[(size_t)r * DDD + col] = v;
          }
        } else if (MODE == 2) {
          int srcn, dstn;
          if (r < NPAIR) {
            int bb = r / PPP;
            srcn = bb * EEE + g.hts[r * 2 + 0];
            dstn = bb * EEE + g.hts[r * 2 + 1];
          } else {
            srcn = dstn = r - NPAIR;
          }
          float vv = v + g.fni[(size_t)srcn * DDD + col] +
                     g.fnj[(size_t)dstn * DDD + col] + g.ebias[col];
          g.Cb[(size_t)r * DDD + col] = f2bf(vv);
          float lrv = vv > 0.f ? vv : 0.2f * vv;
          sp[m][q] += lrv * g.avec[col];
        } else if (MODE == 4) {
          g.nodeWout[((size_t)bz * NNODE + r) * DDD + col] = v;
        } else {   // MODE 3
          int bb = r / PPP;
          int node = bb * EEE + g.hts[r * 2 + bz];
          const float* bias = bz ? g.bias1 : g.bias0;
          float v2 = v + g.nodeW[((size_t)bz * NNODE + node) * DDD + col] + bias[col];
          unsigned short* C = bz ? g.Ct : g.Ch;
          C[(size_t)r * DDD + col] = f2h(tanhf(v2));
        }
      }
    }
  }

  if (MODE == 2) {
    #pragma unroll
    for (int m = 0; m < 2; m++) {
      #pragma unroll
      for (int q = 0; q < 4; q++) {
        float s = sp[m][q];
        s += __shfl_xor(s, 1);
        s += __shfl_xor(s, 2);
        s += __shfl_xor(s, 4);
        s += __shfl_xor(s, 8);
        int r = row0 + wr * 32 + m * 16 + l4 * 4 + q;
        if (l15 == 0 && r < M) atomicAdd(&score_s[r - row0], s);
      }
    }
    __syncthreads();
    if (tid < 64) {
      int r = row0 + tid;
      if (r < M) g.scores[r * HHH + blockIdx.y] = score_s[tid];
    }
  }
}

// ---------------------------------------------------------------------------
// per-node edge softmax over in-edges + message aggregation -> nodes bf16
#define ECAP 256
__global__ __launch_bounds__(256) void k_agg(const float* __restrict__ scores,
                                             const float* __restrict__ fnode,
                                             const int* __restrict__ hts,
                                             unsigned short* __restrict__ nodesb) {
  __shared__ int cnt;
  __shared__ int elist[ECAP], slist[ECAP];
  __shared__ float smax[HHH], ssum[HHH];
  __shared__ float alpha[ECAP * HHH];
  int n = blockIdx.x, tid = threadIdx.x;
  if (tid == 0) cnt = 0;
  __syncthreads();
  for (int e = tid; e < NEDGE; e += 256) {
    int srcn, dstn;
    if (e < NPAIR) {
      int b = e / PPP;
      srcn = b * EEE + hts[e * 2 + 0];
      dstn = b * EEE + hts[e * 2 + 1];
    } else {
      srcn = dstn = e - NPAIR;
    }
    if (dstn == n) {
      int i = atomicAdd(&cnt, 1);
      if (i < ECAP) { elist[i] = e; slist[i] = srcn; }
    }
  }
  __syncthreads();
  int c = min(cnt, ECAP);
  if (tid < HHH) {
    float m = -1e30f;
    for (int i = 0; i < c; i++) m = fmaxf(m, scores[elist[i] * HHH + tid]);
    smax[tid] = m;
    float s = 0.f;
    for (int i = 0; i < c; i++) s += expf(scores[elist[i] * HHH + tid] - m);
    ssum[tid] = s;
  }
  __syncthreads();
  for (int t = tid; t < c * HHH; t += 256) {
    int i = t / HHH, h = t - i * HHH;
    alpha[t] = expf(scores[elist[i] * HHH + h] - smax[h]) / ssum[h];
  }
  __syncthreads();
  for (int j = tid; j < DDD; j += 256) {
    int h = j >> 6;
    float acc = 0.f;
    for (int i = 0; i < c; i++)
      acc += alpha[i * HHH + h] * fnode[(size_t)slist[i] * DDD + j];
    nodesb[(size_t)n * DDD + j] = f2bf(acc);
  }
}

// ---------------------------------------------------------------------------
// Group-bilinear MFMA GEMM, barrier-free, fp16 island (round-13 version).
__global__ __launch_bounds__(256) void k_bilinear_mfma(
    const unsigned short* __restrict__ newh, const unsigned short* __restrict__ newt,
    const unsigned short* __restrict__ tW, float* __restrict__ out) {
  __shared__ unsigned short a_s[64][64];   // [x][p] fp16
  int tid = threadIdx.x;
  int lane = tid & 63;
  int wv = tid >> 6;
  int l15 = lane & 15, l4 = lane >> 4;
  int bid = blockIdx.x;
  int kg = bid / 55, pt = bid - kg * 55;
  bool use1 = ((wv + 4) * 16) < RRR;       // false only for wv==3

  {
    int pl = tid >> 2, xq = (tid & 3) * 16;
    int prow = pt * 64 + pl; if (prow >= NPAIR) prow = NPAIR - 1;
    const unsigned short* src = newh + (size_t)prow * DDD + kg * 64 + xq;
    #pragma unroll
    for (int half16 = 0; half16 < 2; half16++) {
      u16x4 v0 = *(const u16x4*)(src + half16 * 8);
      u16x4 v1 = *(const u16x4*)(src + half16 * 8 + 4);
      #pragma unroll
      for (int i = 0; i < 4; i++) {
        a_s[xq + half16 * 8 + i][pl] = v0[i];
        a_s[xq + half16 * 8 + 4 + i][pl] = v1[i];
      }
    }
  }

  f16x8 bfrag[4][2];
  #pragma unroll
  for (int t = 0; t < 4; t++) {
    int prow = pt * 64 + t * 16 + l15; if (prow >= NPAIR) prow = NPAIR - 1;
    const unsigned short* src = newt + (size_t)prow * DDD + kg * 64 + 8 * l4;
    #pragma unroll
    for (int h = 0; h < 2; h++)
      bfrag[t][h] = __builtin_bit_cast(f16x8, *(const uint4*)(src + h * 32));
  }
  __syncthreads();   // a_s ready; no further barriers

  f32x4 zero = {0.f, 0.f, 0.f, 0.f};
  f32x4 acc[4][2];
  #pragma unroll
  for (int t = 0; t < 4; t++) { acc[t][0] = zero; acc[t][1] = zero; }

  const unsigned short* wp = tW + (size_t)(kg * 64) * 8192 + lane * 8;
  int o00 = (wv * 2 + 0) << 9;
  int o01 = (wv * 2 + 1) << 9;
  int o10 = ((wv + 4) * 2 + 0) << 9;
  int o11 = ((wv + 4) * 2 + 1) << 9;

  auto loadw = [&](uint4* wf, int x) {
    const unsigned short* p = wp + (size_t)x * 8192;
    wf[0] = *(const uint4*)(p + o00);
    wf[1] = *(const uint4*)(p + o01);
    if (use1) {
      wf[2] = *(const uint4*)(p + o10);
      wf[3] = *(const uint4*)(p + o11);
    }
  };
  auto step = [&](const uint4* wf, int x) {
    f16x8 a8[4];
    #pragma unroll
    for (int t = 0; t < 4; t++) {
      unsigned int av = a_s[x][t * 16 + l15];
      unsigned int aw = (av << 16) | av;
      uint4 ab = {aw, aw, aw, aw};
      a8[t] = __builtin_bit_cast(f16x8, ab);
    }
    #pragma unroll
    for (int h = 0; h < 2; h++) {
      f16x8 w0 = __builtin_bit_cast(f16x8, wf[h]);
      f16x8 w1 = __builtin_bit_cast(f16x8, wf[2 + h]);
      #pragma unroll
      for (int t = 0; t < 4; t++) {
        f16x8 gv = a8[t] * bfrag[t][h];     // v_pk_mul_f16
        acc[t][0] = __builtin_amdgcn_mfma_f32_16x16x32_f16(gv, w0, acc[t][0], 0, 0, 0);
        if (use1)
          acc[t][1] = __builtin_amdgcn_mfma_f32_16x16x32_f16(gv, w1, acc[t][1], 0, 0, 0);
      }
    }
  };

  uint4 wa[4], wb[4];
  loadw(wa, 0);
  for (int xx = 0; xx < 64; xx += 2) {
    loadw(wb, xx + 1);
    step(wa, xx);
    if (xx + 2 < 64) loadw(wa, xx + 2);
    step(wb, xx + 1);
  }

  #pragma unroll
  for (int n = 0; n < 2; n++) {
    int r = (wv + 4 * n) * 16 + l15;
    if (r >= RRR) continue;
    #pragma unroll
    for (int t = 0; t < 4; t++) {
      int pbase = pt * 64 + t * 16 + l4 * 4;
      #pragma unroll
      for (int q = 0; q < 4; q++) {
        int p = pbase + q;
        if (p < NPAIR) atomicAdd(&out[(size_t)p * RRR + r], acc[t][n][q]);
      }
    }
  }
}

// ---------------------------------------------------------------------------
extern "C" void kernel_launch(void* const* d_in, const int* in_sizes, int n_in,
                              void* d_out, int out_size, void* d_ws, size_t ws_size,
                              hipStream_t stream) {
  const float* context   = (const float*)d_in[0];
  const float* attention = (const float*)d_in[1];
  const float* mmap      = (const float*)d_in[2];
  const float* emap      = (const float*)d_in[3];
  const int*   hts       = (const int*)d_in[4];
  const float* W_h       = (const float*)d_in[5];
  const float* b_h       = (const float*)d_in[6];
  const float* W_t       = (const float*)d_in[7];
  const float* b_t       = (const float*)d_in[8];
  const float* W_node    = (const float*)d_in[9];
  const float* W_ni      = (const float*)d_in[10];
  const float* W_nj      = (const float*)d_in[11];
  const float* W_fij     = (const float*)d_in[12];
  const float* egat_bias = (const float*)d_in[13];
  const float* attn_vec  = (const float*)d_in[14];
  const float* W_rel     = (const float*)d_in[15];
  const float* b_rel     = (const float*)d_in[16];
  float* out = (float*)d_out;

  float* ws = (float*)d_ws;
  size_t o = 0;
  auto alloc = [&](size_t n) { size_t r = o; o += (n + 63) & ~(size_t)63; return r; };
  auto halloc = [&](size_t nshorts) { return alloc((nshorts + 1) / 2); };  // 16-bit buffers
  size_t o_xb      = halloc((size_t)NNODE * DDD);
  size_t o_ea      = halloc((size_t)BB * EEE * HHH * LLL);
  size_t o_cab     = halloc((size_t)NPAIR * LLL);
  size_t o_ctxT    = halloc((size_t)BB * DDD * LLL);
  size_t o_wtni    = halloc((size_t)DDD * DDD);
  size_t o_wtnj    = halloc((size_t)DDD * DDD);
  size_t o_wtnode  = halloc((size_t)DDD * DDD);
  size_t o_wtfij   = halloc((size_t)DDD * DDD);
  size_t o_wth     = halloc((size_t)DDD * 2 * DDD);
  size_t o_wtt     = halloc((size_t)DDD * 2 * DDD);
  size_t o_cinfob  = halloc((size_t)NPAIR * DDD);
  size_t o_fni     = alloc((size_t)NNODE * DDD);
  size_t o_fnj     = alloc((size_t)NNODE * DDD);
  size_t o_fnode   = alloc((size_t)NNODE * DDD);
  size_t o_foutb   = halloc((size_t)NEDGE * DDD);
  size_t o_scores  = alloc((size_t)NEDGE * HHH);
  size_t o_nodesb  = halloc((size_t)NNODE * DDD);
  size_t o_nodew   = alloc((size_t)2 * NNODE * DDD);  // fp32 [z][node][col]
  size_t o_newh    = halloc((size_t)NPAIR * DDD);     // fp16
  size_t o_newt    = halloc((size_t)NPAIR * DDD);     // fp16
  size_t o_nzl     = alloc((size_t)BB * EEE * LLL);
  size_t o_nzw     = alloc((size_t)BB * EEE * LLL);
  size_t o_nzc     = alloc(128);
  size_t o_tw      = halloc((size_t)768 * 8192);      // 12.6 MB fragment-major fp16
  (void)ws_size; // ~66 MB used

  unsigned short* xb     = (unsigned short*)(ws + o_xb);
  unsigned short* ea     = (unsigned short*)(ws + o_ea);
  unsigned short* cab    = (unsigned short*)(ws + o_cab);
  unsigned short* ctxT   = (unsigned short*)(ws + o_ctxT);
  unsigned short* wtni   = (unsigned short*)(ws + o_wtni);
  unsigned short* wtnj   = (unsigned short*)(ws + o_wtnj);
  unsigned short* wtnode = (unsigned short*)(ws + o_wtnode);
  unsigned short* wtfij  = (unsigned short*)(ws + o_wtfij);
  unsigned short* wth    = (unsigned short*)(ws + o_wth);
  unsigned short* wtt    = (unsigned short*)(ws + o_wtt);
  unsigned short* cinfob = (unsigned short*)(ws + o_cinfob);
  float* fni     = ws + o_fni;
  float* fnj     = ws + o_fnj;
  float* fnode   = ws + o_fnode;
  unsigned short* foutb  = (unsigned short*)(ws + o_foutb);
  float* scores  = ws + o_scores;
  unsigned short* nodesb = (unsigned short*)(ws + o_nodesb);
  float* nodeW   = ws + o_nodew;
  unsigned short* newh   = (unsigned short*)(ws + o_newh);
  unsigned short* newt   = (unsigned short*)(ws + o_newt);
  int*   nzl     = (int*)(ws + o_nzl);
  float* nzw     = ws + o_nzw;
  int*   nzc     = (int*)(ws + o_nzc);
  unsigned short* tW = (unsigned short*)(ws + o_tw);

  // ---- fused prep (em + entity FIRST, then wprep + ctx + 6 W transposes) ----
  PrepArgs pa;
  pa.Wrel = W_rel; pa.context = context; pa.mmap = mmap; pa.emap = emap;
  pa.wsrc[0] = W_ni;  pa.wdst[0] = wtni;
  pa.wsrc[1] = W_nj;  pa.wdst[1] = wtnj;
  pa.wsrc[2] = W_node; pa.wdst[2] = wtnode;
  pa.wsrc[3] = W_fij; pa.wdst[3] = wtfij;
  pa.wsrc[4] = W_h;   pa.wdst[4] = wth;
  pa.wsrc[5] = W_t;   pa.wdst[5] = wtt;
  pa.tW = tW; pa.ctxT = ctxT; pa.xb = xb;
  pa.nzl = nzl; pa.nzw = nzw; pa.nzc = nzc;
  k_prep<<<NB_EM + NB_ENT + NB_WPREP + NB_CTX + NB_WT, 256, 0, stream>>>(pa);

  k_ea<<<dim3(EEE, HHH, BB), 256, 0, stream>>>(attention, nzl, nzw, nzc, ea);
  k_ca<<<BB * PPP, 256, 0, stream>>>(ea, hts, cab, b_rel, out);

  // ---- MODE 5: CINFO (z<4) + FNX (z=4..6) in one dispatch ----
  MGArgs g5 = {};
  g5.A = cab; g5.A2 = xb;
  g5.BT0 = ctxT; g5.BT1 = wtni; g5.BT2 = wtnj; g5.BT3 = wtnode;
  g5.Cb = cinfob; g5.C0 = fni; g5.C1 = fnj; g5.C2 = fnode;
  g5.hts = hts;
  k_mgemm<5><<<dim3(14, 12, 7), 256, 0, stream>>>(g5);

  // ---- MODE 2: FFIJ + fused scores ----
  MGArgs g2 = {};
  g2.A = cinfob; g2.A2 = xb; g2.BT0 = wtfij; g2.Cb = foutb;
  g2.fni = fni; g2.fnj = fnj; g2.ebias = egat_bias; g2.avec = attn_vec;
  g2.scores = scores; g2.hts = hts;
  g2.M = NEDGE; g2.K = DDD; g2.ldb = DDD; g2.koffB = 0;
  k_mgemm<2><<<dim3(57, 12, 1), 256, 0, stream>>>(g2);

  k_agg<<<NNODE, 256, 0, stream>>>(scores, fnode, hts, nodesb);

  // ---- MODE 4: nodeW[z][node] = nodesb @ W_{h,t}[:768] ----
  MGArgs g4 = {};
  g4.A = nodesb; g4.BT0 = wth; g4.BT1 = wtt; g4.nodeWout = nodeW;
  g4.M = NNODE; g4.K = DDD; g4.ldb = 2 * DDD; g4.koffB = 0;
  k_mgemm<4><<<dim3(2, 12, 2), 256, 0, stream>>>(g4);

  // ---- MODE 3: NEWHT (K=768 over foutb; nodeW gathered in epilogue) ----
  MGArgs g3 = {};
  g3.A = foutb; g3.BT0 = wth; g3.BT1 = wtt; g3.nodeW = nodeW;
  g3.bias0 = b_h; g3.bias1 = b_t; g3.Ch = newh; g3.Ct = newt; g3.hts = hts;
  g3.M = NPAIR; g3.K = DDD; g3.ldb = 2 * DDD; g3.koffB = DDD;
  k_mgemm<3><<<dim3(55, 12, 2), 256, 0, stream>>>(g3);

  // ---- bilinear classifier (fp16 island; out pre-initialized in k_ca) ----
  k_bilinear_mfma<<<55 * 12, 256, 0, stream>>>(newh, newt, tW, out);
}